// Round 10
// baseline (385.388 us; speedup 1.0000x reference)
//
#include <hip/hip_runtime.h>

// LSTM autoencoder: 4 layers 64->64, B=512, T=256 — fused, 2 steps/barrier.
//
// 256 blocks x 512 threads (1 block/CU). Block = 2 batch elements x 4 layers.
// Wave w = (layer L = w>>1, unit-half mh = w&1). Datapath = fused11 (best:
// 330us): TRANSPOSED MFMA (C' = act * W^T, lane holds all 4 gates in regs)
// + ds_bpermute redistribute (reg->reg, zero bank conflicts).
//
// ROUND-9 RESTRUCTURE: ~1300 cy/tick of fused11's 3058-cy tick is
// barrier-adjacent overhead (drain-wait + release skew + refill) — it scales
// with BARRIER COUNT. So: 2 timesteps per barrier interval, layer skew 2/layer.
//   interval i, layer L: steps s0 = 2(i-L), s1 = s0+1  (active iff 0<=i-L<128)
//   v(s0), v(s1) = h_{L-1}(s0,s1): produced by L-1 in interval i-1 (its own
//     s0,s1 are the same numbers) -> barrier-ordered, read at interval start.
//   own h(s0-1): written last interval -> barrier-ordered.
//   own h(s0) (needed for step s1): mid-interval PAIR exchange, waves 2L,2L+1
//     only: h write -> lgkmcnt(0) -> flag[wave]=s0 -> poll flag[wave^1]>=s0
//     -> read (DS in-order per wave makes flag-then-data safe; fused9-proven).
//   h ring: 4 slots (slot = s&3). Producer rewrites a slot 2 intervals after
//     the consumer's barrier-ordered read — no hazard. Slot 3 zero-init = h(-1).
// Barriers: 131 (was 259), lgkmcnt(0)-only drain (vmcnt stays in flight).
// L0's x: two prefetch reg-sets (s0,s1), refilled one interval ahead.

typedef _Float16 f16x8 __attribute__((ext_vector_type(8)));
typedef float    f32x4 __attribute__((ext_vector_type(4)));

#define TSEQ 256

__device__ __forceinline__ float fast_rcp(float x) { return __builtin_amdgcn_rcpf(x); }
__device__ __forceinline__ float sigm(float x) { return fast_rcp(1.0f + __expf(-x)); }
__device__ __forceinline__ float tanh_fast(float x) {
    return 2.0f * fast_rcp(1.0f + __expf(-2.0f * x)) - 1.0f;
}
__device__ __forceinline__ f16x8 cvt8(float4 a, float4 b) {
    f16x8 f;
    f[0] = (_Float16)a.x; f[1] = (_Float16)a.y; f[2] = (_Float16)a.z; f[3] = (_Float16)a.w;
    f[4] = (_Float16)b.x; f[5] = (_Float16)b.y; f[6] = (_Float16)b.z; f[7] = (_Float16)b.w;
    return f;
}
__device__ __forceinline__ float bperm(int addr, float v) {
    return __int_as_float(__builtin_amdgcn_ds_bpermute(addr, __float_as_int(v)));
}

__global__ __launch_bounds__(512, 2)
void lstm_fused12(const float* __restrict__ x,     // [512, 256, 64]
                  float* __restrict__ out,         // [512, 256, 64]
                  const float* __restrict__ Wih0, const float* __restrict__ Whh0,
                  const float* __restrict__ bi0,  const float* __restrict__ bh0,
                  const float* __restrict__ Wih1, const float* __restrict__ Whh1,
                  const float* __restrict__ bi1,  const float* __restrict__ bh1,
                  const float* __restrict__ Wih2, const float* __restrict__ Whh2,
                  const float* __restrict__ bi2,  const float* __restrict__ bh2,
                  const float* __restrict__ Wih3, const float* __restrict__ Whh3,
                  const float* __restrict__ bi3,  const float* __restrict__ bh3)
{
    __shared__ _Float16 Hb[4][4][2][64];     // 4 KB: slot (s&3), layer, el(batch), unit
    __shared__ int      Sf[8];               // per-wave pair-exchange flags

    const int tid  = threadIdx.x;
    const int wave = tid >> 6;
    const int lane = tid & 63;
    const int L    = wave >> 1;     // layer 0..3
    const int mh   = wave & 1;      // unit-half: units [mh*32, mh*32+32)
    const int q    = lane >> 4;     // k-quad (MFMA); (s,b) selector (epilogue)
    const int n    = lane & 15;     // B cols; A rows = batch (n&1)
    const int b0   = blockIdx.x * 2;

    const float* Wih = (L == 0) ? Wih0 : (L == 1) ? Wih1 : (L == 2) ? Wih2 : Wih3;
    const float* Whh = (L == 0) ? Whh0 : (L == 1) ? Whh1 : (L == 2) ? Whh2 : Whh3;
    const float* bi  = (L == 0) ? bi0  : (L == 1) ? bi1  : (L == 2) ? bi2  : bi3;
    const float* bh  = (L == 0) ? bh0  : (L == 1) ? bh1  : (L == 2) ? bh2  : bh3;

    // ---- persistent W fragments (MFMA B operand), fused11 layout ----
    f16x8 Bih[4][2][2], Bhh[4][2][2];
#pragma unroll
    for (int g = 0; g < 4; ++g) {
#pragma unroll
        for (int s = 0; s < 2; ++s) {
            const int row = g * 64 + mh * 32 + s * 16 + n;
#pragma unroll
            for (int c = 0; c < 2; ++c) {
                const float* pi = Wih + row * 64 + c * 32 + q * 8;
                const float* ph = Whh + row * 64 + c * 32 + q * 8;
                f16x8 fi, fh;
#pragma unroll
                for (int k = 0; k < 8; ++k) { fi[k] = (_Float16)pi[k]; fh[k] = (_Float16)ph[k]; }
                Bih[g][s][c] = fi;
                Bhh[g][s][c] = fh;
            }
        }
    }

    // ---- epilogue identity: el = lane>>5 (batch), unit = mh*32 + (lane&31) ----
    const int eu = lane & 31;
    const int el = lane >> 5;
    const int unit = mh * 32 + eu;
    float4 be;
    be.x = bi[unit]       + bh[unit];
    be.y = bi[64 + unit]  + bh[64 + unit];
    be.z = bi[128 + unit] + bh[128 + unit];
    be.w = bi[192 + unit] + bh[192 + unit];
    float cst = 0.0f;
    float* outp = out + ((size_t)(b0 + el) * TSEQ) * 64 + unit;   // L==3 only

    const int baddr = n * 4;        // bpermute: pull from source lane (lane&15)

    // ---- zero h ring (4 slots, 4096 B = 1024 ints) + flags ----
    ((int*)Hb)[tid] = 0;
    ((int*)Hb)[tid + 512] = 0;
    if (tid < 8) Sf[tid] = -2;

    // ---- L0 x prefetch: two sets (s0, s1), lanes n<2 only ----
    const float* xbase = x + ((size_t)(b0 + (n & 1)) * TSEQ) * 64 + q * 8;
    float4 A0, A1, A2, A3, B0, B1, B2, B3;
    A0 = A1 = A2 = A3 = make_float4(0.f, 0.f, 0.f, 0.f);
    B0 = B1 = B2 = B3 = A0;
    if (L == 0 && n < 2) {
        A0 = *(const float4*)(xbase);      A1 = *(const float4*)(xbase + 4);
        A2 = *(const float4*)(xbase + 32); A3 = *(const float4*)(xbase + 36);
        B0 = *(const float4*)(xbase + 64);  B1 = *(const float4*)(xbase + 68);
        B2 = *(const float4*)(xbase + 96);  B3 = *(const float4*)(xbase + 100);
    }

    __syncthreads();   // init visible to all waves

    const f32x4 z4 = {0.f, 0.f, 0.f, 0.f};
    const int NI = 131;              // L=3 last active: i-3=127 -> i=130

    for (int i = 0; i < NI; ++i) {
        const bool act = (unsigned)(i - L) < 128u;   // wave-uniform
        if (act) {
            const int s0 = 2 * (i - L);
            const int s1 = s0 + 1;

            // ---- interval-start fragment reads (all barrier-ordered) ----
            f16x8 vfA0, vfA1, vfB0, vfB1;
            if (L == 0) {
                vfA0 = cvt8(A0, A1);  vfA1 = cvt8(A2, A3);   // x(s0)
                vfB0 = cvt8(B0, B1);  vfB1 = cvt8(B2, B3);   // x(s1)
                if (s0 + 2 < TSEQ && n < 2) {                // prefetch next interval
                    const float* p = xbase + (size_t)(s0 + 2) * 64;
                    A0 = *(const float4*)(p);      A1 = *(const float4*)(p + 4);
                    A2 = *(const float4*)(p + 32); A3 = *(const float4*)(p + 36);
                    if (s0 + 3 < TSEQ) {
                        B0 = *(const float4*)(p + 64); B1 = *(const float4*)(p + 68);
                        B2 = *(const float4*)(p + 96); B3 = *(const float4*)(p + 100);
                    }
                }
            } else {
                const _Float16* va = &Hb[s0 & 3][L - 1][n & 1][0];
                vfA0 = *(const f16x8*)(va + q * 8);
                vfA1 = *(const f16x8*)(va + 32 + q * 8);
                const _Float16* vb = &Hb[s1 & 3][L - 1][n & 1][0];
                vfB0 = *(const f16x8*)(vb + q * 8);
                vfB1 = *(const f16x8*)(vb + 32 + q * 8);
            }
            const _Float16* hp = &Hb[(s0 - 1) & 3][L][n & 1][0];
            f16x8 hf0 = *(const f16x8*)(hp + q * 8);
            f16x8 hf1 = *(const f16x8*)(hp + 32 + q * 8);

            // ================= step s0 =================
            f32x4 Cgs[2][4];
#pragma unroll
            for (int s = 0; s < 2; ++s) {
#pragma unroll
                for (int g = 0; g < 4; ++g) {
                    f32x4 c;
                    c = __builtin_amdgcn_mfma_f32_16x16x32_f16(hf0, Bhh[g][s][0], z4, 0, 0, 0);
                    c = __builtin_amdgcn_mfma_f32_16x16x32_f16(hf1, Bhh[g][s][1], c,  0, 0, 0);
                    c = __builtin_amdgcn_mfma_f32_16x16x32_f16(vfA0, Bih[g][s][0], c,  0, 0, 0);
                    Cgs[s][g] = __builtin_amdgcn_mfma_f32_16x16x32_f16(vfA1, Bih[g][s][1], c, 0, 0, 0);
                }
            }
            float gv[4];
#pragma unroll
            for (int g = 0; g < 4; ++g) {
                float v00 = bperm(baddr, Cgs[0][g][0]);
                float v10 = bperm(baddr, Cgs[1][g][0]);
                float v01 = bperm(baddr, Cgs[0][g][1]);
                float v11 = bperm(baddr, Cgs[1][g][1]);
                float lo = (q & 1) ? v10 : v00;
                float hi = (q & 1) ? v11 : v01;
                gv[g] = (q & 2) ? hi : lo;
            }
            {
                float gi = sigm(gv[0] + be.x);
                float gf = sigm(gv[1] + be.y);
                float gg = tanh_fast(gv[2] + be.z);
                float go = sigm(gv[3] + be.w);
                cst = gf * cst + gi * gg;
                float h = go * tanh_fast(cst);
                if (L == 3) outp[(size_t)s0 * 64] = h;
                Hb[s0 & 3][L][el][unit] = (_Float16)h;
            }

            // ---- pair exchange: publish h(s0), wait for pair's half ----
            asm volatile("s_waitcnt lgkmcnt(0)" ::: "memory");
            if (lane == 0) ((volatile int*)Sf)[wave] = s0;
            for (;;) {
                asm volatile("" ::: "memory");
                int pv = ((volatile int*)Sf)[wave ^ 1];
                if (pv >= s0) break;
                __builtin_amdgcn_s_sleep(1);
            }
            const _Float16* hq = &Hb[s0 & 3][L][n & 1][0];
            f16x8 hg0 = *(const f16x8*)(hq + q * 8);
            f16x8 hg1 = *(const f16x8*)(hq + 32 + q * 8);

            // ================= step s1 =================
#pragma unroll
            for (int s = 0; s < 2; ++s) {
#pragma unroll
                for (int g = 0; g < 4; ++g) {
                    f32x4 c;
                    c = __builtin_amdgcn_mfma_f32_16x16x32_f16(hg0, Bhh[g][s][0], z4, 0, 0, 0);
                    c = __builtin_amdgcn_mfma_f32_16x16x32_f16(hg1, Bhh[g][s][1], c,  0, 0, 0);
                    c = __builtin_amdgcn_mfma_f32_16x16x32_f16(vfB0, Bih[g][s][0], c,  0, 0, 0);
                    Cgs[s][g] = __builtin_amdgcn_mfma_f32_16x16x32_f16(vfB1, Bih[g][s][1], c, 0, 0, 0);
                }
            }
#pragma unroll
            for (int g = 0; g < 4; ++g) {
                float v00 = bperm(baddr, Cgs[0][g][0]);
                float v10 = bperm(baddr, Cgs[1][g][0]);
                float v01 = bperm(baddr, Cgs[0][g][1]);
                float v11 = bperm(baddr, Cgs[1][g][1]);
                float lo = (q & 1) ? v10 : v00;
                float hi = (q & 1) ? v11 : v01;
                gv[g] = (q & 2) ? hi : lo;
            }
            {
                float gi = sigm(gv[0] + be.x);
                float gf = sigm(gv[1] + be.y);
                float gg = tanh_fast(gv[2] + be.z);
                float go = sigm(gv[3] + be.w);
                cst = gf * cst + gi * gg;
                float h = go * tanh_fast(cst);
                if (L == 3) outp[(size_t)s1 * 64] = h;
                Hb[s1 & 3][L][el][unit] = (_Float16)h;
            }
        }
        // ---- one barrier per interval: drain LDS only ----
        __builtin_amdgcn_sched_barrier(0);
        asm volatile("s_waitcnt lgkmcnt(0)" ::: "memory");
        __builtin_amdgcn_s_barrier();
        __builtin_amdgcn_sched_barrier(0);
    }
}

extern "C" void kernel_launch(void* const* d_in, const int* in_sizes, int n_in,
                              void* d_out, int out_size, void* d_ws, size_t ws_size,
                              hipStream_t stream) {
    const float* x = (const float*)d_in[0];
    float* out = (float*)d_out;

    lstm_fused12<<<256, 512, 0, stream>>>(
        x, out,
        (const float*)d_in[1],  (const float*)d_in[2],
        (const float*)d_in[3],  (const float*)d_in[4],
        (const float*)d_in[5],  (const float*)d_in[6],
        (const float*)d_in[7],  (const float*)d_in[8],
        (const float*)d_in[9],  (const float*)d_in[10],
        (const float*)d_in[11], (const float*)d_in[12],
        (const float*)d_in[13], (const float*)d_in[14],
        (const float*)d_in[15], (const float*)d_in[16]);
}

// Round 11
// 353.658 us; speedup vs baseline: 1.0897x; 1.0897x over previous
//
#include <hip/hip_runtime.h>

// LSTM autoencoder: 4 layers 64->64, B=512, T=256 — fused, 2 steps/barrier,
// SHARED-Wih MFMA packing (48 MFMA/interval, was 64).
//
// 256 blocks x 512 threads (1 block/CU). Block = 2 batch elements x 4 layers.
// Wave w = (layer L = w>>1, unit-half mh = w&1). Transposed MFMA (C'=act*W^T)
// + ds_bpermute redistribute (fused11) + 2-step intervals w/ pair-flag
// mid-exchange (fused12).
//
// ROUND-10: gates(s) = Wih*v(s) + Whh*h(s-1). Both v(s0),v(s1) are known at
// interval start (producer wrote them last interval, barrier-ordered), so:
//   A1 rows 0-1 = v(s0) batches, rows 2-3 = v(s1) batches (lanes n=2,3 read
//     slot s1&3, batch n&1; lanes n>=4 dup -> garbage rows, never read)
//   C = Bih-chain(A1)            : rows0-1 = Wih*v(s0), rows2-3 = Wih*v(s1)
//   C = Bhh-chain(A2) + C, A2 rows2-3 ZEROED (lanes n=2,3 supply 0)
//                                : rows0-1 = full gates(s0), rows2-3 kept
//   s0 epilogue: bperm regs 0,1 -> h(s0) -> pair exchange (flag protocol)
//   C = Bhh-chain(A3) + C, A3 = h(s0) via natural n&1 dup (rows2-3 = batches)
//                                : rows2-3 = full gates(s1)
//   s1 epilogue: bperm regs 2,3
// MFMA: 16+16+16 = 48/interval (was 64); s1 chain is 2-deep (was 4).
// Barriers: 131, lgkmcnt(0)-only drain (vmcnt stays in flight).
// L0 x: per-lane prefetch, lanes n<4 carry (batch n&1, time s0+(n>>1)).

typedef _Float16 f16x8 __attribute__((ext_vector_type(8)));
typedef float    f32x4 __attribute__((ext_vector_type(4)));

#define TSEQ 256

__device__ __forceinline__ float fast_rcp(float x) { return __builtin_amdgcn_rcpf(x); }
__device__ __forceinline__ float sigm(float x) { return fast_rcp(1.0f + __expf(-x)); }
__device__ __forceinline__ float tanh_fast(float x) {
    return 2.0f * fast_rcp(1.0f + __expf(-2.0f * x)) - 1.0f;
}
__device__ __forceinline__ f16x8 cvt8(float4 a, float4 b) {
    f16x8 f;
    f[0] = (_Float16)a.x; f[1] = (_Float16)a.y; f[2] = (_Float16)a.z; f[3] = (_Float16)a.w;
    f[4] = (_Float16)b.x; f[5] = (_Float16)b.y; f[6] = (_Float16)b.z; f[7] = (_Float16)b.w;
    return f;
}
__device__ __forceinline__ float bperm(int addr, float v) {
    return __int_as_float(__builtin_amdgcn_ds_bpermute(addr, __float_as_int(v)));
}

__global__ __launch_bounds__(512, 2)
void lstm_fused13(const float* __restrict__ x,     // [512, 256, 64]
                  float* __restrict__ out,         // [512, 256, 64]
                  const float* __restrict__ Wih0, const float* __restrict__ Whh0,
                  const float* __restrict__ bi0,  const float* __restrict__ bh0,
                  const float* __restrict__ Wih1, const float* __restrict__ Whh1,
                  const float* __restrict__ bi1,  const float* __restrict__ bh1,
                  const float* __restrict__ Wih2, const float* __restrict__ Whh2,
                  const float* __restrict__ bi2,  const float* __restrict__ bh2,
                  const float* __restrict__ Wih3, const float* __restrict__ Whh3,
                  const float* __restrict__ bi3,  const float* __restrict__ bh3)
{
    __shared__ _Float16 Hb[4][4][2][64];     // 4 KB: slot (s&3), layer, el(batch), unit
    __shared__ int      Sf[8];               // per-wave pair-exchange flags

    const int tid  = threadIdx.x;
    const int wave = tid >> 6;
    const int lane = tid & 63;
    const int L    = wave >> 1;     // layer 0..3
    const int mh   = wave & 1;      // unit-half: units [mh*32, mh*32+32)
    const int q    = lane >> 4;     // k-quad (MFMA); (s,b) selector (epilogue)
    const int n    = lane & 15;     // A rows; n<2 -> s0 batches, n=2,3 -> s1 batches
    const int b0   = blockIdx.x * 2;
    const int lsel = (n >> 1) == 1; // 1 for lanes n=2,3 (the s1 rows)

    const float* Wih = (L == 0) ? Wih0 : (L == 1) ? Wih1 : (L == 2) ? Wih2 : Wih3;
    const float* Whh = (L == 0) ? Whh0 : (L == 1) ? Whh1 : (L == 2) ? Whh2 : Whh3;
    const float* bi  = (L == 0) ? bi0  : (L == 1) ? bi1  : (L == 2) ? bi2  : bi3;
    const float* bh  = (L == 0) ? bh0  : (L == 1) ? bh1  : (L == 2) ? bh2  : bh3;

    // ---- persistent W fragments (MFMA B operand), fused11 layout ----
    // B[k=q*8+kk][col=n] = W[row][c*32+q*8+kk], row = g*64+mh*32+s*16+n.
    f16x8 Bih[4][2][2], Bhh[4][2][2];
#pragma unroll
    for (int g = 0; g < 4; ++g) {
#pragma unroll
        for (int s = 0; s < 2; ++s) {
            const int row = g * 64 + mh * 32 + s * 16 + n;
#pragma unroll
            for (int c = 0; c < 2; ++c) {
                const float* pi = Wih + row * 64 + c * 32 + q * 8;
                const float* ph = Whh + row * 64 + c * 32 + q * 8;
                f16x8 fi, fh;
#pragma unroll
                for (int k = 0; k < 8; ++k) { fi[k] = (_Float16)pi[k]; fh[k] = (_Float16)ph[k]; }
                Bih[g][s][c] = fi;
                Bhh[g][s][c] = fh;
            }
        }
    }

    // ---- epilogue identity: el = lane>>5 (batch), unit = mh*32 + (lane&31) ----
    const int eu = lane & 31;
    const int el = lane >> 5;
    const int unit = mh * 32 + eu;
    float4 be;
    be.x = bi[unit]       + bh[unit];
    be.y = bi[64 + unit]  + bh[64 + unit];
    be.z = bi[128 + unit] + bh[128 + unit];
    be.w = bi[192 + unit] + bh[192 + unit];
    float cst = 0.0f;
    float* outp = out + ((size_t)(b0 + el) * TSEQ) * 64 + unit;   // L==3 only

    const int baddr = n * 4;        // bpermute: pull from source lane (lane&15)

    // ---- zero h ring (4 slots, 4096 B = 1024 ints) + flags ----
    ((int*)Hb)[tid] = 0;
    ((int*)Hb)[tid + 512] = 0;
    if (tid < 8) Sf[tid] = -2;

    // ---- L0 x prefetch: lanes n<4, per-lane (batch n&1, time s0+(n>>1)) ----
    const float* xbase = x + ((size_t)(b0 + (n & 1)) * TSEQ) * 64 + q * 8;
    float4 R0, R1, R2, R3;
    R0 = R1 = R2 = R3 = make_float4(0.f, 0.f, 0.f, 0.f);
    if (L == 0 && n < 4) {
        const float* p = xbase + (size_t)(n >> 1) * 64;   // t = 0 or 1
        R0 = *(const float4*)(p);      R1 = *(const float4*)(p + 4);
        R2 = *(const float4*)(p + 32); R3 = *(const float4*)(p + 36);
    }

    __syncthreads();   // init visible to all waves

    const f32x4 z4 = {0.f, 0.f, 0.f, 0.f};
    const int NI = 131;              // L=3 last active: i-3=127 -> i=130

    for (int i = 0; i < NI; ++i) {
        const bool act = (unsigned)(i - L) < 128u;   // wave-uniform
        if (act) {
            const int s0 = 2 * (i - L);
            const int s1 = s0 + 1;
            const int p2 = (s0 & 3);         // = 2*parity: slot of s0; s1 -> p2+1
            const int sprev = (s0 - 1) & 3;  // slot of s0-1

            // ---- A1: v rows — n<2: v(s0) batch n; n=2,3: v(s1) batch n&1 ----
            f16x8 vf0, vf1;
            if (L == 0) {
                vf0 = cvt8(R0, R1);
                vf1 = cvt8(R2, R3);
                if (n < 4) {                  // prefetch next interval's x
                    const int tl = s0 + 2 + (n >> 1);
                    if (tl < TSEQ) {
                        const float* p = xbase + (size_t)tl * 64;
                        R0 = *(const float4*)(p);      R1 = *(const float4*)(p + 4);
                        R2 = *(const float4*)(p + 32); R3 = *(const float4*)(p + 36);
                    }
                }
            } else {
                const _Float16* vp = &Hb[p2 + lsel][L - 1][n & 1][0];
                vf0 = *(const f16x8*)(vp + q * 8);
                vf1 = *(const f16x8*)(vp + 32 + q * 8);
            }
            // ---- A2: h(s0-1) rows 0-1 (dup 4-15); rows 2-3 ZERO ----
            f16x8 hf0, hf1;
            {
                const _Float16* hp = &Hb[sprev][L][n & 1][0];
                hf0 = *(const f16x8*)(hp + q * 8);
                hf1 = *(const f16x8*)(hp + 32 + q * 8);
                if (lsel) {
#pragma unroll
                    for (int k = 0; k < 8; ++k) { hf0[k] = (_Float16)0.f; hf1[k] = (_Float16)0.f; }
                }
            }

            // ---- 32 MFMA: Bih chain (both steps) then Bhh(s0-1) chain ----
            f32x4 Cgs[2][4];
#pragma unroll
            for (int s = 0; s < 2; ++s) {
#pragma unroll
                for (int g = 0; g < 4; ++g) {
                    f32x4 c;
                    c = __builtin_amdgcn_mfma_f32_16x16x32_f16(vf0, Bih[g][s][0], z4, 0, 0, 0);
                    c = __builtin_amdgcn_mfma_f32_16x16x32_f16(vf1, Bih[g][s][1], c,  0, 0, 0);
                    c = __builtin_amdgcn_mfma_f32_16x16x32_f16(hf0, Bhh[g][s][0], c,  0, 0, 0);
                    Cgs[s][g] = __builtin_amdgcn_mfma_f32_16x16x32_f16(hf1, Bhh[g][s][1], c, 0, 0, 0);
                }
            }

            // ================= step s0 epilogue (regs 0,1) =================
            float gv[4];
#pragma unroll
            for (int g = 0; g < 4; ++g) {
                float v00 = bperm(baddr, Cgs[0][g][0]);
                float v10 = bperm(baddr, Cgs[1][g][0]);
                float v01 = bperm(baddr, Cgs[0][g][1]);
                float v11 = bperm(baddr, Cgs[1][g][1]);
                float lo = (q & 1) ? v10 : v00;
                float hi = (q & 1) ? v11 : v01;
                gv[g] = (q & 2) ? hi : lo;
            }
            {
                float gi = sigm(gv[0] + be.x);
                float gf = sigm(gv[1] + be.y);
                float gg = tanh_fast(gv[2] + be.z);
                float go = sigm(gv[3] + be.w);
                cst = gf * cst + gi * gg;
                float h = go * tanh_fast(cst);
                if (L == 3) outp[(size_t)s0 * 64] = h;
                Hb[p2][L][el][unit] = (_Float16)h;
            }

            // ---- pair exchange: publish h(s0), wait for pair's half ----
            asm volatile("s_waitcnt lgkmcnt(0)" ::: "memory");
            if (lane == 0) ((volatile int*)Sf)[wave] = s0;
            for (;;) {
                asm volatile("" ::: "memory");
                int pv = ((volatile int*)Sf)[wave ^ 1];
                if (pv >= s0) break;
                __builtin_amdgcn_s_sleep(1);
            }
            // ---- A3: h(s0), natural n&1 dup (rows 2-3 = batches 0,1) ----
            const _Float16* hq = &Hb[p2][L][n & 1][0];
            f16x8 hg0 = *(const f16x8*)(hq + q * 8);
            f16x8 hg1 = *(const f16x8*)(hq + 32 + q * 8);

            // ---- 16 MFMA: Bhh(s0) chain onto kept rows 2-3 ----
#pragma unroll
            for (int s = 0; s < 2; ++s) {
#pragma unroll
                for (int g = 0; g < 4; ++g) {
                    f32x4 c;
                    c = __builtin_amdgcn_mfma_f32_16x16x32_f16(hg0, Bhh[g][s][0], Cgs[s][g], 0, 0, 0);
                    Cgs[s][g] = __builtin_amdgcn_mfma_f32_16x16x32_f16(hg1, Bhh[g][s][1], c, 0, 0, 0);
                }
            }

            // ================= step s1 epilogue (regs 2,3) =================
#pragma unroll
            for (int g = 0; g < 4; ++g) {
                float v00 = bperm(baddr, Cgs[0][g][2]);
                float v10 = bperm(baddr, Cgs[1][g][2]);
                float v01 = bperm(baddr, Cgs[0][g][3]);
                float v11 = bperm(baddr, Cgs[1][g][3]);
                float lo = (q & 1) ? v10 : v00;
                float hi = (q & 1) ? v11 : v01;
                gv[g] = (q & 2) ? hi : lo;
            }
            {
                float gi = sigm(gv[0] + be.x);
                float gf = sigm(gv[1] + be.y);
                float gg = tanh_fast(gv[2] + be.z);
                float go = sigm(gv[3] + be.w);
                cst = gf * cst + gi * gg;
                float h = go * tanh_fast(cst);
                if (L == 3) outp[(size_t)s1 * 64] = h;
                Hb[p2 + 1][L][el][unit] = (_Float16)h;
            }
        }
        // ---- one barrier per interval: drain LDS only ----
        __builtin_amdgcn_sched_barrier(0);
        asm volatile("s_waitcnt lgkmcnt(0)" ::: "memory");
        __builtin_amdgcn_s_barrier();
        __builtin_amdgcn_sched_barrier(0);
    }
}

extern "C" void kernel_launch(void* const* d_in, const int* in_sizes, int n_in,
                              void* d_out, int out_size, void* d_ws, size_t ws_size,
                              hipStream_t stream) {
    const float* x = (const float*)d_in[0];
    float* out = (float*)d_out;

    lstm_fused13<<<256, 512, 0, stream>>>(
        x, out,
        (const float*)d_in[1],  (const float*)d_in[2],
        (const float*)d_in[3],  (const float*)d_in[4],
        (const float*)d_in[5],  (const float*)d_in[6],
        (const float*)d_in[7],  (const float*)d_in[8],
        (const float*)d_in[9],  (const float*)d_in[10],
        (const float*)d_in[11], (const float*)d_in[12],
        (const float*)d_in[13], (const float*)d_in[14],
        (const float*)d_in[15], (const float*)d_in[16]);
}

// Round 12
// 325.450 us; speedup vs baseline: 1.1842x; 1.0867x over previous
//
#include <hip/hip_runtime.h>

// LSTM autoencoder: 4 layers 64->64, B=512, T=256 — fused, 4 steps/barrier,
// shared-Wih MFMA packing (80 MFMA/interval = 20/step).
//
// 256 blocks x 512 threads (1 block/CU). Block = 2 batch elements x 4 layers.
// Wave w = (layer L = w>>1, unit-half mh = w&1). Transposed MFMA (C'=act*W^T)
// + ds_bpermute redistribute (fused11) + pair-flag mid-exchange (fused12)
// + shared-Wih row packing (fused13), extended to 4 steps:
//   A rows 0-7 = (step (n>>1)&3, batch n&1); rows 8-15 dup/garbage (unused).
//   C = Bih-chain(A)                  [16 MFMA] : rows 2j,2j+1 = Wih*v(s0+j)
//   for j = 0..3:
//     C += Bhh-chain(h(s0+j-1)), rows!=2j,2j+1 zeroed     [16 MFMA]
//     epilogue j: bperm regs {(j&1)*2,+1} from q-group (j>>1) -> h(s0+j)
//     publish flag s0+j (j<3); chain j+1 polls pair flag >= s0+j
//   j=0's h(s0-1) is barrier-ordered (prev interval); h ring = 8 slots
//   (s&7) so this interval's writes (g0..g0+3) never touch the slots the
//   consumer layer reads this interval (g0+4..g0+7 mod 8).
// Hb[layer][slot][el][72]: 144B row pad -> packed v-read (8 lanes, 4 slots
// x 2 el) hits 8 distinct banks; zero conflicts.
// Barriers: 67 (was 131), lgkmcnt(0)-only drain (vmcnt stays in flight).
// L0 x: lanes n<8 prefetch (batch n&1, t = s0+(n>>1)&3) one interval ahead.

typedef _Float16 f16x8 __attribute__((ext_vector_type(8)));
typedef float    f32x4 __attribute__((ext_vector_type(4)));

#define TSEQ 256

__device__ __forceinline__ float fast_rcp(float x) { return __builtin_amdgcn_rcpf(x); }
__device__ __forceinline__ float sigm(float x) { return fast_rcp(1.0f + __expf(-x)); }
__device__ __forceinline__ float tanh_fast(float x) {
    return 2.0f * fast_rcp(1.0f + __expf(-2.0f * x)) - 1.0f;
}
__device__ __forceinline__ f16x8 cvt8(float4 a, float4 b) {
    f16x8 f;
    f[0] = (_Float16)a.x; f[1] = (_Float16)a.y; f[2] = (_Float16)a.z; f[3] = (_Float16)a.w;
    f[4] = (_Float16)b.x; f[5] = (_Float16)b.y; f[6] = (_Float16)b.z; f[7] = (_Float16)b.w;
    return f;
}
__device__ __forceinline__ float bperm(int addr, float v) {
    return __int_as_float(__builtin_amdgcn_ds_bpermute(addr, __float_as_int(v)));
}

__global__ __launch_bounds__(512, 2)
void lstm_fused14(const float* __restrict__ x,     // [512, 256, 64]
                  float* __restrict__ out,         // [512, 256, 64]
                  const float* __restrict__ Wih0, const float* __restrict__ Whh0,
                  const float* __restrict__ bi0,  const float* __restrict__ bh0,
                  const float* __restrict__ Wih1, const float* __restrict__ Whh1,
                  const float* __restrict__ bi1,  const float* __restrict__ bh1,
                  const float* __restrict__ Wih2, const float* __restrict__ Whh2,
                  const float* __restrict__ bi2,  const float* __restrict__ bh2,
                  const float* __restrict__ Wih3, const float* __restrict__ Whh3,
                  const float* __restrict__ bi3,  const float* __restrict__ bh3)
{
    __shared__ _Float16 Hb[4][8][2][72];     // 9216 B: layer, slot (s&7), el, unit+pad
    __shared__ int      Sf[8];               // per-wave pair-exchange flags

    const int tid  = threadIdx.x;
    const int wave = tid >> 6;
    const int lane = tid & 63;
    const int L    = wave >> 1;     // layer 0..3
    const int mh   = wave & 1;      // unit-half: units [mh*32, mh*32+32)
    const int q    = lane >> 4;     // k-quad (MFMA); (stile,batch) selector (epilogue)
    const int n    = lane & 15;     // A rows: (step (n>>1)&3, batch n&1)
    const int stp  = (n >> 1) & 3;  // packed step-row selector
    const int b0   = blockIdx.x * 2;

    const float* Wih = (L == 0) ? Wih0 : (L == 1) ? Wih1 : (L == 2) ? Wih2 : Wih3;
    const float* Whh = (L == 0) ? Whh0 : (L == 1) ? Whh1 : (L == 2) ? Whh2 : Whh3;
    const float* bi  = (L == 0) ? bi0  : (L == 1) ? bi1  : (L == 2) ? bi2  : bi3;
    const float* bh  = (L == 0) ? bh0  : (L == 1) ? bh1  : (L == 2) ? bh2  : bh3;

    // ---- persistent W fragments (MFMA B operand) ----
    // B[k=q*8+kk][col=n] = W[row][c*32+q*8+kk], row = g*64+mh*32+s*16+n.
    f16x8 Bih[4][2][2], Bhh[4][2][2];
#pragma unroll
    for (int g = 0; g < 4; ++g) {
#pragma unroll
        for (int s = 0; s < 2; ++s) {
            const int row = g * 64 + mh * 32 + s * 16 + n;
#pragma unroll
            for (int c = 0; c < 2; ++c) {
                const float* pi = Wih + row * 64 + c * 32 + q * 8;
                const float* ph = Whh + row * 64 + c * 32 + q * 8;
                f16x8 fi, fh;
#pragma unroll
                for (int k = 0; k < 8; ++k) { fi[k] = (_Float16)pi[k]; fh[k] = (_Float16)ph[k]; }
                Bih[g][s][c] = fi;
                Bhh[g][s][c] = fh;
            }
        }
    }

    // ---- epilogue identity: el = lane>>5 (batch), unit = mh*32 + (lane&31) ----
    const int eu = lane & 31;
    const int el = lane >> 5;
    const int unit = mh * 32 + eu;
    float4 be;
    be.x = bi[unit]       + bh[unit];
    be.y = bi[64 + unit]  + bh[64 + unit];
    be.z = bi[128 + unit] + bh[128 + unit];
    be.w = bi[192 + unit] + bh[192 + unit];
    float cst = 0.0f;
    float* outp = out + ((size_t)(b0 + el) * TSEQ) * 64 + unit;   // L==3 only

    // ---- zero h ring (9216 B = 2304 ints) + flags ----
    for (int iz = tid; iz < 2304; iz += 512) ((int*)Hb)[iz] = 0;
    if (tid < 8) Sf[tid] = -2;

    // ---- L0 x prefetch: lanes n<8, (batch n&1, t = stp) ----
    const float* xbase = x + ((size_t)(b0 + (n & 1)) * TSEQ) * 64 + q * 8;
    float4 R0, R1, R2, R3;
    R0 = R1 = R2 = R3 = make_float4(0.f, 0.f, 0.f, 0.f);
    if (L == 0 && n < 8) {
        const float* p = xbase + (size_t)stp * 64;
        R0 = *(const float4*)(p);      R1 = *(const float4*)(p + 4);
        R2 = *(const float4*)(p + 32); R3 = *(const float4*)(p + 36);
    }

    __syncthreads();   // init visible to all waves

    const f32x4 z4 = {0.f, 0.f, 0.f, 0.f};
    const int NI = 67;               // L=3 last active: i-3=63 -> i=66

// One step: masked Bhh chain + epilogue. J, R0I/R1I (C regs), QS (src q-group)
// are literal macro args -> all vector indices compile-time (rule #20).
#define DO_STEP(J, R0I, R1I, QS)                                              \
    {                                                                         \
        if ((J) > 0) {                                                        \
            const int need = s0 + (J) - 1;                                    \
            for (;;) {                                                        \
                asm volatile("" ::: "memory");                                \
                int pv = ((volatile int*)Sf)[wave ^ 1];                       \
                if (pv >= need) break;                                        \
                __builtin_amdgcn_s_sleep(1);                                  \
            }                                                                 \
        }                                                                     \
        f16x8 hf0, hf1;                                                       \
        _Pragma("unroll")                                                     \
        for (int k = 0; k < 8; ++k) { hf0[k] = (_Float16)0.f; hf1[k] = (_Float16)0.f; } \
        if (stp == (J)) {                                                     \
            const _Float16* hp = &Hb[L][(s0 + (J) - 1) & 7][n & 1][0];        \
            hf0 = *(const f16x8*)(hp + q * 8);                                \
            hf1 = *(const f16x8*)(hp + 32 + q * 8);                           \
        }                                                                     \
        _Pragma("unroll")                                                     \
        for (int s = 0; s < 2; ++s) {                                         \
            _Pragma("unroll")                                                 \
            for (int g = 0; g < 4; ++g) {                                     \
                f32x4 c;                                                      \
                c = __builtin_amdgcn_mfma_f32_16x16x32_f16(hf0, Bhh[g][s][0], Cgs[s][g], 0, 0, 0); \
                Cgs[s][g] = __builtin_amdgcn_mfma_f32_16x16x32_f16(hf1, Bhh[g][s][1], c, 0, 0, 0); \
            }                                                                 \
        }                                                                     \
        const int ba = (((QS) << 4) + n) * 4;                                 \
        float gv[4];                                                          \
        _Pragma("unroll")                                                     \
        for (int g = 0; g < 4; ++g) {                                         \
            float v00 = bperm(ba, Cgs[0][g][R0I]);                            \
            float v10 = bperm(ba, Cgs[1][g][R0I]);                            \
            float v01 = bperm(ba, Cgs[0][g][R1I]);                            \
            float v11 = bperm(ba, Cgs[1][g][R1I]);                            \
            float lo = (q & 1) ? v10 : v00;                                   \
            float hi = (q & 1) ? v11 : v01;                                   \
            gv[g] = (q & 2) ? hi : lo;                                        \
        }                                                                     \
        {                                                                     \
            float gi = sigm(gv[0] + be.x);                                    \
            float gf = sigm(gv[1] + be.y);                                    \
            float gg = tanh_fast(gv[2] + be.z);                               \
            float go = sigm(gv[3] + be.w);                                    \
            cst = gf * cst + gi * gg;                                         \
            float h = go * tanh_fast(cst);                                    \
            if (L == 3) outp[(size_t)(s0 + (J)) * 64] = h;                    \
            Hb[L][(s0 + (J)) & 7][el][unit] = (_Float16)h;                    \
        }                                                                     \
        if ((J) < 3) {                                                        \
            asm volatile("s_waitcnt lgkmcnt(0)" ::: "memory");                \
            if (lane == 0) ((volatile int*)Sf)[wave] = s0 + (J);              \
        }                                                                     \
    }

    for (int i = 0; i < NI; ++i) {
        const bool act = (unsigned)(i - L) < 64u;   // wave-uniform
        if (act) {
            const int s0 = 4 * (i - L);
            const int g0 = s0 & 7;          // slot group base: 0 or 4

            // ---- A1: packed v rows (step stp, batch n&1) ----
            f16x8 vf0, vf1;
            if (L == 0) {
                vf0 = cvt8(R0, R1);
                vf1 = cvt8(R2, R3);
                if (n < 8) {                 // prefetch next interval's x
                    const int tl = s0 + 4 + stp;
                    if (tl < TSEQ) {
                        const float* p = xbase + (size_t)tl * 64;
                        R0 = *(const float4*)(p);      R1 = *(const float4*)(p + 4);
                        R2 = *(const float4*)(p + 32); R3 = *(const float4*)(p + 36);
                    }
                }
            } else {
                const _Float16* vp = &Hb[L - 1][g0 + stp][n & 1][0];
                vf0 = *(const f16x8*)(vp + q * 8);
                vf1 = *(const f16x8*)(vp + 32 + q * 8);
            }

            // ---- Bih chain: 16 MFMA, all 4 steps' input part ----
            f32x4 Cgs[2][4];
#pragma unroll
            for (int s = 0; s < 2; ++s) {
#pragma unroll
                for (int g = 0; g < 4; ++g) {
                    f32x4 c;
                    c = __builtin_amdgcn_mfma_f32_16x16x32_f16(vf0, Bih[g][s][0], z4, 0, 0, 0);
                    Cgs[s][g] = __builtin_amdgcn_mfma_f32_16x16x32_f16(vf1, Bih[g][s][1], c, 0, 0, 0);
                }
            }

            // ---- 4 chained steps: rows {0,1},{2,3} from q0; {4,5},{6,7} q1 ----
            DO_STEP(0, 0, 1, 0)
            DO_STEP(1, 2, 3, 0)
            DO_STEP(2, 0, 1, 1)
            DO_STEP(3, 2, 3, 1)
        }
        // ---- one barrier per interval: drain LDS only ----
        __builtin_amdgcn_sched_barrier(0);
        asm volatile("s_waitcnt lgkmcnt(0)" ::: "memory");
        __builtin_amdgcn_s_barrier();
        __builtin_amdgcn_sched_barrier(0);
    }
#undef DO_STEP
}

extern "C" void kernel_launch(void* const* d_in, const int* in_sizes, int n_in,
                              void* d_out, int out_size, void* d_ws, size_t ws_size,
                              hipStream_t stream) {
    const float* x = (const float*)d_in[0];
    float* out = (float*)d_out;

    lstm_fused14<<<256, 512, 0, stream>>>(
        x, out,
        (const float*)d_in[1],  (const float*)d_in[2],
        (const float*)d_in[3],  (const float*)d_in[4],
        (const float*)d_in[5],  (const float*)d_in[6],
        (const float*)d_in[7],  (const float*)d_in[8],
        (const float*)d_in[9],  (const float*)d_in[10],
        (const float*)d_in[11], (const float*)d_in[12],
        (const float*)d_in[13], (const float*)d_in[14],
        (const float*)d_in[15], (const float*)d_in[16]);
}